// Round 12
// baseline (317.492 us; speedup 1.0000x reference)
//
#include <hip/hip_runtime.h>
#include <stdint.h>

// DotAtt: B=16, Lq=Lk=2048, D=64. scores = 64*Q.K^T ; softmax over q (axis=-2);
// JAX threefry dropout p=0.1 (key 42, partitionable, bits=x0^x1); out = W.V
// Pass 0: pre-split Q,K -> bf16 hi/lo in ws (shared by both passes).
// Pass 1: column stats M[k], R[k]=1/(0.9*Z[k]) via split-bf16 MFMA scores.
// Pass 2: O = (exp(s-M)*R*keep) . V, same MFMA chain (bitwise-identical s).

#define LQ 2048
#define DD 64
#define NQ (16 * LQ * DD)   // 2,097,152 elems per tensor

typedef short bf16x8 __attribute__((ext_vector_type(8)));
typedef float f32x4 __attribute__((ext_vector_type(4)));
typedef unsigned short ushort_t;

#define MFMA16(a, b, c) __builtin_amdgcn_mfma_f32_16x16x32_bf16(a, b, c, 0, 0, 0)

__device__ __forceinline__ ushort_t f2bf(float x) {
  uint32_t u = __float_as_uint(x);
  return (ushort_t)((u + 0x7FFFu + ((u >> 16) & 1u)) >> 16);  // RNE
}
__device__ __forceinline__ float bf2f(ushort_t h) {
  return __uint_as_float(((uint32_t)h) << 16);
}

// 16x16 score tile, K-dim 64 as 2 halves, 3 split terms. SAME order in both
// passes so s is bitwise identical (M consistency).
__device__ __forceinline__ f32x4 score6(bf16x8 Ah0, bf16x8 Ah1, bf16x8 Al0, bf16x8 Al1,
                                        bf16x8 Bh0, bf16x8 Bh1, bf16x8 Bl0, bf16x8 Bl1) {
  f32x4 acc = {0.f, 0.f, 0.f, 0.f};
  acc = MFMA16(Ah0, Bh0, acc);
  acc = MFMA16(Ah1, Bh1, acc);
  acc = MFMA16(Al0, Bh0, acc);
  acc = MFMA16(Al1, Bh1, acc);
  acc = MFMA16(Ah0, Bl0, acc);
  acc = MFMA16(Ah1, Bl1, acc);
  return acc;
}

__device__ __forceinline__ void tf_round(uint32_t& x0, uint32_t& x1, const int r) {
  x0 += x1;
  x1 = (x1 << r) | (x1 >> (32 - r));
  x1 ^= x0;
}

// JAX threefry2x32 partitionable draw: bits = x0^x1, key=(0,42), ctr=(0,j). Verified r9.
__device__ __forceinline__ bool keep_bit(uint32_t j) {
  const uint32_t ks1 = 42u, ks2 = 0x1BD11BDAu ^ 42u;
  uint32_t x0 = 0u;
  uint32_t x1 = j + ks1;
  tf_round(x0,x1,13); tf_round(x0,x1,15); tf_round(x0,x1,26); tf_round(x0,x1,6);
  x0 += ks1; x1 += ks2 + 1u;
  tf_round(x0,x1,17); tf_round(x0,x1,29); tf_round(x0,x1,16); tf_round(x0,x1,24);
  x0 += ks2; x1 += 0u + 2u;
  tf_round(x0,x1,13); tf_round(x0,x1,15); tf_round(x0,x1,26); tf_round(x0,x1,6);
  x0 += 0u; x1 += ks1 + 3u;
  tf_round(x0,x1,17); tf_round(x0,x1,29); tf_round(x0,x1,16); tf_round(x0,x1,24);
  x0 += ks1; x1 += ks2 + 4u;
  tf_round(x0,x1,13); tf_round(x0,x1,15); tf_round(x0,x1,26); tf_round(x0,x1,6);
  x0 += ks2; x1 += 0u + 5u;
  uint32_t bits = x0 ^ x1;
  float u = __uint_as_float((bits >> 9) | 0x3F800000u) - 1.0f;
  return u < 0.9f;
}

// ---------------- Pass 0: pre-split Q,K -> bf16 hi/lo -----------------------
__global__ __launch_bounds__(256) void split_qk(
    const float* __restrict__ Q, const float* __restrict__ K,
    ushort_t* __restrict__ Qh, ushort_t* __restrict__ Ql,
    ushort_t* __restrict__ Kh, ushort_t* __restrict__ Kl) {
  const int total4 = (2 * NQ) / 4;          // 1,048,576 float4 groups
  const int stride = 1024 * 256;
  for (int i = blockIdx.x * 256 + threadIdx.x; i < total4; i += stride) {
    const bool isK = i >= NQ / 4;           // wave-uniform (NQ/4 % 64 == 0)
    const int j = isK ? i - NQ / 4 : i;
    float4 v = ((const float4*)(isK ? K : Q))[j];
    short4 h, l;
    ushort_t t;
    t = f2bf(v.x); h.x = (short)t; l.x = (short)f2bf(v.x - bf2f(t));
    t = f2bf(v.y); h.y = (short)t; l.y = (short)f2bf(v.y - bf2f(t));
    t = f2bf(v.z); h.z = (short)t; l.z = (short)f2bf(v.z - bf2f(t));
    t = f2bf(v.w); h.w = (short)t; l.w = (short)f2bf(v.w - bf2f(t));
    *(short4*)&(isK ? Kh : Qh)[(size_t)j * 4] = h;
    *(short4*)&(isK ? Kl : Ql)[(size_t)j * 4] = l;
  }
}

// ---------------- Pass 1: per-(b,k) column max & inv-sum (MFMA) -------------
// 512 blocks (b, ktile64) x 512 thr. Wave g: k-cols 16*(g&3), q-team g>>2
// (team0 = even q-tiles, team1 = odd). K frags in regs; Q frags fragment-major LDS.
__global__ __launch_bounds__(512) void dotatt_colstats(
    const ushort_t* __restrict__ Qh, const ushort_t* __restrict__ Ql,
    const ushort_t* __restrict__ Kh, const ushort_t* __restrict__ Kl,
    float* __restrict__ Mcol, float* __restrict__ Rcol) {
  __shared__ ushort_t qf[2][4][4][64][8];   // [team][qtile][frag][lane][8] = 32KB
  __shared__ float2 mz8[8][16];

  const int bid = blockIdx.x;
  const int b = bid >> 5;
  const int kbase = (bid & 31) << 6;
  const int tid = threadIdx.x;
  const int lane = tid & 63;
  const int g = tid >> 6;
  const int kr = lane & 15;
  const int d0 = (lane >> 4) << 3;
  const int c = g & 3;
  const int team = g >> 2;

  // K frags once (row kbase + 16c + kr)
  const size_t krow = ((size_t)b * LQ + kbase + (c << 4) + kr) * DD;
  bf16x8 Bh0 = *(const bf16x8*)&Kh[krow + d0];
  bf16x8 Bh1 = *(const bf16x8*)&Kh[krow + d0 + 32];
  bf16x8 Bl0 = *(const bf16x8*)&Kl[krow + d0];
  bf16x8 Bl1 = *(const bf16x8*)&Kl[krow + d0 + 32];

  const size_t qb = (size_t)b * LQ * DD;
  float m = -1e30f, z = 0.f;

#pragma unroll 1
  for (int su = 0; su < 16; ++su) {
    // stage tiles 2su (team0) and 2su+1 (team1): 2048 16B slots, 4/thread
#pragma unroll
    for (int i = 0; i < 4; ++i) {
      int s = tid + (i << 9);
      int tm = (s >> 10) & 1, qt = (s >> 8) & 3, f = (s >> 6) & 3, ln = s & 63;
      int srow = ((su << 1) + tm) * 64 + (qt << 4) + (ln & 15);
      int scol = ((ln >> 4) << 3) + ((f & 1) << 5);
      const ushort_t* src = (f < 2) ? Qh : Ql;
      *(bf16x8*)&qf[tm][qt][f][ln][0] =
          *(const bf16x8*)&src[qb + (size_t)srow * DD + scol];
    }
    __syncthreads();

    float s16[16];
#pragma unroll
    for (int qt = 0; qt < 4; ++qt) {
      bf16x8 Ah0 = *(const bf16x8*)&qf[team][qt][0][lane][0];
      bf16x8 Ah1 = *(const bf16x8*)&qf[team][qt][1][lane][0];
      bf16x8 Al0 = *(const bf16x8*)&qf[team][qt][2][lane][0];
      bf16x8 Al1 = *(const bf16x8*)&qf[team][qt][3][lane][0];
      f32x4 s = score6(Ah0, Ah1, Al0, Al1, Bh0, Bh1, Bl0, Bl1);
#pragma unroll
      for (int r = 0; r < 4; ++r) s16[(qt << 2) + r] = s[r] * 64.f;
    }
    __syncthreads();

    float mx = s16[0];
#pragma unroll
    for (int i = 1; i < 16; ++i) mx = fmaxf(mx, s16[i]);
    if (!__all(mx < m - 20.f)) {
      float mn = fmaxf(m, mx);
      float zz = 0.f;
#pragma unroll
      for (int i = 0; i < 16; ++i) zz += __expf(s16[i] - mn);
      z = z * __expf(m - mn) + zz;
      m = mn;
    }
  }
  // merge hi groups (disjoint q subsets, same col)
#pragma unroll
  for (int off = 16; off < 64; off <<= 1) {
    float om = __shfl_xor(m, off);
    float oz = __shfl_xor(z, off);
    float mn = fmaxf(m, om);
    z = z * __expf(m - mn) + oz * __expf(om - mn);
    m = mn;
  }
  // merge teams
  if (lane < 16) mz8[g][lane] = make_float2(m, z);
  __syncthreads();
  if (g < 4 && lane < 16) {
    float2 A = mz8[g][lane], Bv = mz8[g + 4][lane];
    float M = fmaxf(A.x, Bv.x);
    float Z = A.y * __expf(A.x - M) + Bv.y * __expf(Bv.x - M);
    size_t o = (size_t)b * LQ + kbase + (g << 4) + lane;
    Mcol[o] = M;
    Rcol[o] = 1.0f / (0.9f * Z);
  }
}

// ---------------- Pass 2: O[q,:] = sum_k exp(s-M)*R*keep * V[k,:] -----------
// 512 blocks (b, qtile64) x 512 thr. Wave g owns k-eighth (256 k, 16 iters);
// Q frags staged once fragment-major; Slds bounce -> lane=q PV with skip.
__global__ __launch_bounds__(512, 4) void dotatt_out(
    const float* __restrict__ V,
    const ushort_t* __restrict__ Qh, const ushort_t* __restrict__ Ql,
    const ushort_t* __restrict__ Kh, const ushort_t* __restrict__ Kl,
    const float* __restrict__ Mcol, const float* __restrict__ Rcol,
    float* __restrict__ Out) {
  __shared__ ushort_t qf[4][4][64][8];   // [qtile][frag][lane][8] = 16KB
  __shared__ float Slds[8][64][17];      // wave-private S tiles (34816B); epilogue reuse

  const int bid = blockIdx.x;
  const int b = bid >> 5;
  const int qbase = (bid & 31) << 6;
  const int tid = threadIdx.x;
  const int lane = tid & 63;
  const int g = tid >> 6;
  const int kr = lane & 15;
  const int hi = lane >> 4;
  const int d0 = hi << 3;

  const size_t qb = (size_t)b * LQ * DD;
  // stage Q frags once: 1024 16B slots, 2/thread
#pragma unroll
  for (int i = 0; i < 2; ++i) {
    int s = tid + (i << 9);
    int qt = (s >> 8) & 3, f = (s >> 6) & 3, ln = s & 63;
    int srow = qbase + (qt << 4) + (ln & 15);
    int scol = ((ln >> 4) << 3) + ((f & 1) << 5);
    const ushort_t* src = (f < 2) ? Qh : Ql;
    *(bf16x8*)&qf[qt][f][ln][0] =
        *(const bf16x8*)&src[qb + (size_t)srow * DD + scol];
  }
  __syncthreads();

  float acc[64];
#pragma unroll
  for (int d = 0; d < 64; ++d) acc[d] = 0.f;

  const float* Vb = V + qb;
  const float* Mb = Mcol + (size_t)b * LQ;
  const float* Rb = Rcol + (size_t)b * LQ;
  const uint32_t jrow = ((uint32_t)b * LQ + (uint32_t)(qbase + lane)) * (uint32_t)LQ;

#pragma unroll 1
  for (int t = 0; t < 16; ++t) {
    const int k0 = (g << 8) + (t << 4);
    const size_t krow = qb + (size_t)(k0 + kr) * DD;
    bf16x8 Bh0 = *(const bf16x8*)&Kh[krow + d0];
    bf16x8 Bh1 = *(const bf16x8*)&Kh[krow + d0 + 32];
    bf16x8 Bl0 = *(const bf16x8*)&Kl[krow + d0];
    bf16x8 Bl1 = *(const bf16x8*)&Kl[krow + d0 + 32];
    const float Mw = Mb[k0 + kr];
    const float rr = Rb[k0 + kr];

    float sm[16];
#pragma unroll
    for (int qt = 0; qt < 4; ++qt) {
      bf16x8 Ah0 = *(const bf16x8*)&qf[qt][0][lane][0];
      bf16x8 Ah1 = *(const bf16x8*)&qf[qt][1][lane][0];
      bf16x8 Al0 = *(const bf16x8*)&qf[qt][2][lane][0];
      bf16x8 Al1 = *(const bf16x8*)&qf[qt][3][lane][0];
      f32x4 s = score6(Ah0, Ah1, Al0, Al1, Bh0, Bh1, Bl0, Bl1);
#pragma unroll
      for (int r = 0; r < 4; ++r) sm[(qt << 2) + r] = s[r] * 64.f - Mw;
    }
    float mx = sm[0];
#pragma unroll
    for (int i = 1; i < 16; ++i) mx = fmaxf(mx, sm[i]);
    if (__all(mx < -25.f)) continue;          // whole 64q x 16k chunk negligible

    // bounce S to wave-private LDS (lane holds col kr, rows qt*16+hi*4+r)
#pragma unroll
    for (int qt = 0; qt < 4; ++qt)
#pragma unroll
      for (int r = 0; r < 4; ++r)
        Slds[g][(qt << 4) + (hi << 2) + r][kr] = sm[(qt << 2) + r];

#pragma unroll 1
    for (int kk = 0; kk < 16; ++kk) {
      float smv = Slds[g][lane][kk];          // lane = q row
      if (__all(smv < -25.f)) continue;
      float Rk = __shfl(rr, kk);
      float w = __expf(smv) * Rk;
      if (!keep_bit(jrow + (uint32_t)(k0 + kk))) w = 0.f;
      const float4* vrow = (const float4*)(Vb + (size_t)(k0 + kk) * DD);  // uniform broadcast
#pragma unroll
      for (int c4 = 0; c4 < 16; ++c4) {
        float4 vv = vrow[c4];
        acc[4 * c4 + 0] += w * vv.x;
        acc[4 * c4 + 1] += w * vv.y;
        acc[4 * c4 + 2] += w * vv.z;
        acc[4 * c4 + 3] += w * vv.w;
      }
    }
  }

  __syncthreads();
  // reduce 8 wave-partials (reuse Slds region: 64*68 f32 = 17408B < 34816B)
  float (*qs)[68] = (float(*)[68])&Slds[0][0][0];
  for (int gg = 0; gg < 8; ++gg) {
    if (g == gg) {
      if (gg == 0) {
#pragma unroll
        for (int d = 0; d < 64; ++d) qs[lane][d] = acc[d];
      } else {
#pragma unroll
        for (int d = 0; d < 64; ++d) qs[lane][d] += acc[d];
      }
    }
    __syncthreads();
  }

  float* Ob = Out + ((size_t)b * LQ + qbase) * DD;
#pragma unroll
  for (int i = 0; i < 2; ++i) {
    int idx = tid + (i << 9);
    int r = idx >> 4, c4 = idx & 15;
    ((float4*)Ob)[idx] = *(const float4*)&qs[r][c4 * 4];
  }
}

extern "C" void kernel_launch(void* const* d_in, const int* in_sizes, int n_in,
                              void* d_out, int out_size, void* d_ws, size_t ws_size,
                              hipStream_t stream) {
  const float* Q = (const float*)d_in[0];
  const float* K = (const float*)d_in[1];
  const float* V = (const float*)d_in[2];
  float* Out = (float*)d_out;

  ushort_t* Qh = (ushort_t*)d_ws;           // 4MB each
  ushort_t* Ql = Qh + NQ;
  ushort_t* Kh = Ql + NQ;
  ushort_t* Kl = Kh + NQ;
  float* Mcol = (float*)(Kl + NQ);          // 128KB
  float* Rcol = Mcol + (size_t)16 * LQ;     // 128KB  (total ~16.3MB)

  hipLaunchKernelGGL(split_qk, dim3(1024), dim3(256), 0, stream,
                     Q, K, Qh, Ql, Kh, Kl);
  hipLaunchKernelGGL(dotatt_colstats, dim3(16 * 32), dim3(512), 0, stream,
                     Qh, Ql, Kh, Kl, Mcol, Rcol);
  hipLaunchKernelGGL(dotatt_out, dim3(16 * 32), dim3(512), 0, stream,
                     V, Qh, Ql, Kh, Kl, Mcol, Rcol, Out);
}

// Round 14
// 273.417 us; speedup vs baseline: 1.1612x; 1.1612x over previous
//
#include <hip/hip_runtime.h>
#include <stdint.h>

// DotAtt: B=16, Lq=Lk=2048, D=64. scores = 64*Q.K^T ; softmax over q (axis=-2);
// JAX threefry dropout p=0.1 (key 42, partitionable, bits=x0^x1); out = W.V
// Pass 0: pre-split Q,K -> bf16 hi/lo in ws; zero Out.
// Pass 1: partial column stats (m,z) per q-half, barrier-free, MFMA scores.
// Pass 2: O += (exp(s-M)*R*keep) . V per k-half, atomicAdd into zeroed Out.
// M/R merged inline from the two partials -- identical FP ops in every block.

#define LQ 2048
#define DD 64
#define NQ (16 * LQ * DD)   // 2,097,152 elems per tensor

typedef short bf16x8 __attribute__((ext_vector_type(8)));
typedef float f32x4 __attribute__((ext_vector_type(4)));
typedef unsigned short ushort_t;

#define MFMA16(a, b, c) __builtin_amdgcn_mfma_f32_16x16x32_bf16(a, b, c, 0, 0, 0)

__device__ __forceinline__ ushort_t f2bf(float x) {
  uint32_t u = __float_as_uint(x);
  return (ushort_t)((u + 0x7FFFu + ((u >> 16) & 1u)) >> 16);  // RNE
}
__device__ __forceinline__ float bf2f(ushort_t h) {
  return __uint_as_float(((uint32_t)h) << 16);
}

// 16x16 score tile, K-dim 64 as 2 halves, 3 split terms. SAME order in both
// passes so s is bitwise identical (M consistency).
__device__ __forceinline__ f32x4 score6(bf16x8 Ah0, bf16x8 Ah1, bf16x8 Al0, bf16x8 Al1,
                                        bf16x8 Bh0, bf16x8 Bh1, bf16x8 Bl0, bf16x8 Bl1) {
  f32x4 acc = {0.f, 0.f, 0.f, 0.f};
  acc = MFMA16(Ah0, Bh0, acc);
  acc = MFMA16(Ah1, Bh1, acc);
  acc = MFMA16(Al0, Bh0, acc);
  acc = MFMA16(Al1, Bh1, acc);
  acc = MFMA16(Ah0, Bl0, acc);
  acc = MFMA16(Ah1, Bl1, acc);
  return acc;
}

__device__ __forceinline__ void tf_round(uint32_t& x0, uint32_t& x1, const int r) {
  x0 += x1;
  x1 = (x1 << r) | (x1 >> (32 - r));
  x1 ^= x0;
}

// JAX threefry2x32 partitionable draw: bits = x0^x1, key=(0,42), ctr=(0,j). Verified r9.
__device__ __forceinline__ bool keep_bit(uint32_t j) {
  const uint32_t ks1 = 42u, ks2 = 0x1BD11BDAu ^ 42u;
  uint32_t x0 = 0u;
  uint32_t x1 = j + ks1;
  tf_round(x0,x1,13); tf_round(x0,x1,15); tf_round(x0,x1,26); tf_round(x0,x1,6);
  x0 += ks1; x1 += ks2 + 1u;
  tf_round(x0,x1,17); tf_round(x0,x1,29); tf_round(x0,x1,16); tf_round(x0,x1,24);
  x0 += ks2; x1 += 0u + 2u;
  tf_round(x0,x1,13); tf_round(x0,x1,15); tf_round(x0,x1,26); tf_round(x0,x1,6);
  x0 += 0u; x1 += ks1 + 3u;
  tf_round(x0,x1,17); tf_round(x0,x1,29); tf_round(x0,x1,16); tf_round(x0,x1,24);
  x0 += ks1; x1 += ks2 + 4u;
  tf_round(x0,x1,13); tf_round(x0,x1,15); tf_round(x0,x1,26); tf_round(x0,x1,6);
  x0 += ks2; x1 += 0u + 5u;
  uint32_t bits = x0 ^ x1;
  float u = __uint_as_float((bits >> 9) | 0x3F800000u) - 1.0f;
  return u < 0.9f;
}

// ---------------- Pass 0: pre-split Q,K -> bf16 hi/lo; zero Out -------------
__global__ __launch_bounds__(256) void split_qk(
    const float* __restrict__ Q, const float* __restrict__ K,
    ushort_t* __restrict__ Qh, ushort_t* __restrict__ Ql,
    ushort_t* __restrict__ Kh, ushort_t* __restrict__ Kl,
    float* __restrict__ Out) {
  const int total4 = (2 * NQ) / 4;          // 1,048,576 float4 groups
  const int stride = 1024 * 256;
  const int base = blockIdx.x * 256 + threadIdx.x;
  for (int i = base; i < total4; i += stride) {
    const bool isK = i >= NQ / 4;           // wave-uniform (NQ/4 % 64 == 0)
    const int j = isK ? i - NQ / 4 : i;
    float4 v = ((const float4*)(isK ? K : Q))[j];
    short4 h, l;
    ushort_t t;
    t = f2bf(v.x); h.x = (short)t; l.x = (short)f2bf(v.x - bf2f(t));
    t = f2bf(v.y); h.y = (short)t; l.y = (short)f2bf(v.y - bf2f(t));
    t = f2bf(v.z); h.z = (short)t; l.z = (short)f2bf(v.z - bf2f(t));
    t = f2bf(v.w); h.w = (short)t; l.w = (short)f2bf(v.w - bf2f(t));
    *(short4*)&(isK ? Kh : Qh)[(size_t)j * 4] = h;
    *(short4*)&(isK ? Kl : Ql)[(size_t)j * 4] = l;
  }
  const float4 z4 = {0.f, 0.f, 0.f, 0.f};
  for (int i = base; i < NQ / 4; i += stride) ((float4*)Out)[i] = z4;
}

// ---------------- Pass 1: partial column stats, barrier-free ----------------
// 1024 blocks = b(16) x ktile(32) x qhalf(2); 256 thr. Wave g owns 16 k-cols,
// scans its q-half (1024 rows, 32x2 tiles). No LDS, no barriers.
__global__ __launch_bounds__(256) void dotatt_colstats(
    const ushort_t* __restrict__ Qh, const ushort_t* __restrict__ Ql,
    const ushort_t* __restrict__ Kh, const ushort_t* __restrict__ Kl,
    float2* __restrict__ MZpart) {
  const int bid = blockIdx.x;
  const int b = bid >> 6;
  const int ktile = (bid >> 1) & 31;
  const int half = bid & 1;
  const int tid = threadIdx.x;
  const int lane = tid & 63;
  const int g = tid >> 6;
  const int kr = lane & 15;
  const int d0 = (lane >> 4) << 3;
  const int col = (ktile << 6) + (g << 4) + kr;

  const size_t qb = (size_t)b * LQ * DD;
  const size_t krow = qb + (size_t)col * DD;
  bf16x8 Bh0 = *(const bf16x8*)&Kh[krow + d0];
  bf16x8 Bh1 = *(const bf16x8*)&Kh[krow + d0 + 32];
  bf16x8 Bl0 = *(const bf16x8*)&Kl[krow + d0];
  bf16x8 Bl1 = *(const bf16x8*)&Kl[krow + d0 + 32];

  const int q0 = half << 10;
  float m = -1e30f, z = 0.f;

#pragma unroll 1
  for (int it = 0; it < 32; ++it) {
#pragma unroll
    for (int j = 0; j < 2; ++j) {
      const int row = q0 + (it << 5) + (j << 4) + kr;
      const size_t qrow = qb + (size_t)row * DD;
      bf16x8 Ah0 = *(const bf16x8*)&Qh[qrow + d0];
      bf16x8 Ah1 = *(const bf16x8*)&Qh[qrow + d0 + 32];
      bf16x8 Al0 = *(const bf16x8*)&Ql[qrow + d0];
      bf16x8 Al1 = *(const bf16x8*)&Ql[qrow + d0 + 32];
      f32x4 s = score6(Ah0, Ah1, Al0, Al1, Bh0, Bh1, Bl0, Bl1);
      float s0 = s[0] * 64.f, s1 = s[1] * 64.f, s2 = s[2] * 64.f, s3 = s[3] * 64.f;
      float mx = fmaxf(fmaxf(s0, s1), fmaxf(s2, s3));
      if (!__all(mx < m - 20.f)) {
        float mn = fmaxf(m, mx);
        z = z * __expf(m - mn) + __expf(s0 - mn) + __expf(s1 - mn)
          + __expf(s2 - mn) + __expf(s3 - mn);
        m = mn;
      }
    }
  }
  // merge hi groups (disjoint q subsets, same col)
#pragma unroll
  for (int off = 16; off < 64; off <<= 1) {
    float om = __shfl_xor(m, off);
    float oz = __shfl_xor(z, off);
    float mn = fmaxf(m, om);
    z = z * __expf(m - mn) + oz * __expf(om - mn);
    m = mn;
  }
  if (lane < 16)
    MZpart[((size_t)half * 16 + b) * LQ + col] = make_float2(m, z);
}

// ---------------- Pass 2: O += (exp(s-M)*R*keep) . V per k-half -------------
// 1024 blocks = b(16) x qtile(32) x khalf(2); 256 thr. Wave g owns 256 k
// (16 iters). Q frags fragment-major LDS; Slds bounce; atomicAdd epilogue.
__global__ __launch_bounds__(256) void dotatt_out(
    const float* __restrict__ V,
    const ushort_t* __restrict__ Qh, const ushort_t* __restrict__ Ql,
    const ushort_t* __restrict__ Kh, const ushort_t* __restrict__ Kl,
    const float2* __restrict__ MZpart, float* __restrict__ Out) {
  __shared__ ushort_t qf[4][4][64][8];   // [qtile][frag][lane][8] = 16KB
  __shared__ float Slds[4][64][17];      // wave-private S tiles; epilogue reuse

  const int bid = blockIdx.x;
  const int b = bid >> 6;
  const int qbase = ((bid >> 1) & 31) << 6;
  const int khalf = bid & 1;
  const int tid = threadIdx.x;
  const int lane = tid & 63;
  const int g = tid >> 6;
  const int kr = lane & 15;
  const int hi = lane >> 4;
  const int d0 = hi << 3;

  const size_t qb = (size_t)b * LQ * DD;
  // stage Q frags once: 1024 16B slots, 4/thread
#pragma unroll
  for (int i = 0; i < 4; ++i) {
    int s = tid + (i << 8);
    int qt = (s >> 8) & 3, f = (s >> 6) & 3, ln = s & 63;
    int srow = qbase + (qt << 4) + (ln & 15);
    int scol = ((ln >> 4) << 3) + ((f & 1) << 5);
    const ushort_t* src = (f < 2) ? Qh : Ql;
    *(bf16x8*)&qf[qt][f][ln][0] =
        *(const bf16x8*)&src[qb + (size_t)srow * DD + scol];
  }
  __syncthreads();

  float acc[64];
#pragma unroll
  for (int d = 0; d < 64; ++d) acc[d] = 0.f;

  const float* Vb = V + qb;
  const float2* MZ0 = MZpart + (size_t)b * LQ;
  const float2* MZ1 = MZpart + ((size_t)16 + b) * LQ;
  const uint32_t jrow = ((uint32_t)b * LQ + (uint32_t)(qbase + lane)) * (uint32_t)LQ;

#pragma unroll 1
  for (int t = 0; t < 16; ++t) {
    const int k0 = (khalf << 10) + (g << 8) + (t << 4);
    const size_t krow = qb + (size_t)(k0 + kr) * DD;
    bf16x8 Bh0 = *(const bf16x8*)&Kh[krow + d0];
    bf16x8 Bh1 = *(const bf16x8*)&Kh[krow + d0 + 32];
    bf16x8 Bl0 = *(const bf16x8*)&Kl[krow + d0];
    bf16x8 Bl1 = *(const bf16x8*)&Kl[krow + d0 + 32];
    // merge the two partial stats (identical FP ops in every block)
    float2 p0 = MZ0[k0 + kr];
    float2 p1 = MZ1[k0 + kr];
    const float Mw = fmaxf(p0.x, p1.x);
    const float Zw = p0.y * __expf(p0.x - Mw) + p1.y * __expf(p1.x - Mw);
    const float rr = 1.0f / (0.9f * Zw);

    float sm[16];
#pragma unroll
    for (int qt = 0; qt < 4; ++qt) {
      bf16x8 Ah0 = *(const bf16x8*)&qf[qt][0][lane][0];
      bf16x8 Ah1 = *(const bf16x8*)&qf[qt][1][lane][0];
      bf16x8 Al0 = *(const bf16x8*)&qf[qt][2][lane][0];
      bf16x8 Al1 = *(const bf16x8*)&qf[qt][3][lane][0];
      f32x4 s = score6(Ah0, Ah1, Al0, Al1, Bh0, Bh1, Bl0, Bl1);
#pragma unroll
      for (int r = 0; r < 4; ++r) sm[(qt << 2) + r] = s[r] * 64.f - Mw;
    }
    float mx = sm[0];
#pragma unroll
    for (int i = 1; i < 16; ++i) mx = fmaxf(mx, sm[i]);
    if (__all(mx < -25.f)) continue;          // whole 64q x 16k chunk negligible

    // bounce S to wave-private LDS (lane holds col kr, rows qt*16+hi*4+r)
#pragma unroll
    for (int qt = 0; qt < 4; ++qt)
#pragma unroll
      for (int r = 0; r < 4; ++r)
        Slds[g][(qt << 4) + (hi << 2) + r][kr] = sm[(qt << 2) + r];

#pragma unroll 1
    for (int kk = 0; kk < 16; ++kk) {
      float smv = Slds[g][lane][kk];          // lane = q row
      if (__all(smv < -25.f)) continue;
      float Rk = __shfl(rr, kk);
      float w = __expf(smv) * Rk;
      if (!keep_bit(jrow + (uint32_t)(k0 + kk))) w = 0.f;
      const float4* vrow = (const float4*)(Vb + (size_t)(k0 + kk) * DD);  // uniform broadcast
#pragma unroll
      for (int c4 = 0; c4 < 16; ++c4) {
        float4 vv = vrow[c4];
        acc[4 * c4 + 0] += w * vv.x;
        acc[4 * c4 + 1] += w * vv.y;
        acc[4 * c4 + 2] += w * vv.z;
        acc[4 * c4 + 3] += w * vv.w;
      }
    }
  }

  __syncthreads();
  // reduce 4 wave-partials (reuse Slds region: 64*68 = 4352 f32 = 4*64*17)
  float (*qs)[68] = (float(*)[68])&Slds[0][0][0];
  for (int gg = 0; gg < 4; ++gg) {
    if (g == gg) {
      if (gg == 0) {
#pragma unroll
        for (int d = 0; d < 64; ++d) qs[lane][d] = acc[d];
      } else {
#pragma unroll
        for (int d = 0; d < 64; ++d) qs[lane][d] += acc[d];
      }
    }
    __syncthreads();
  }

  float* Ob = Out + ((size_t)b * LQ + qbase) * DD;
#pragma unroll
  for (int i = 0; i < 16; ++i) {
    int idx = tid + (i << 8);          // 0..4095
    int r = idx >> 6, c = idx & 63;
    atomicAdd(&Ob[(size_t)r * DD + c], qs[r][c]);
  }
}

extern "C" void kernel_launch(void* const* d_in, const int* in_sizes, int n_in,
                              void* d_out, int out_size, void* d_ws, size_t ws_size,
                              hipStream_t stream) {
  const float* Q = (const float*)d_in[0];
  const float* K = (const float*)d_in[1];
  const float* V = (const float*)d_in[2];
  float* Out = (float*)d_out;

  ushort_t* Qh = (ushort_t*)d_ws;           // 4MB each
  ushort_t* Ql = Qh + NQ;
  ushort_t* Kh = Ql + NQ;
  ushort_t* Kl = Kh + NQ;
  float2* MZpart = (float2*)(Kl + NQ);      // 2*16*2048 float2 = 512KB (~16.8MB total)

  hipLaunchKernelGGL(split_qk, dim3(1024), dim3(256), 0, stream,
                     Q, K, Qh, Ql, Kh, Kl, Out);
  hipLaunchKernelGGL(dotatt_colstats, dim3(1024), dim3(256), 0, stream,
                     Qh, Ql, Kh, Kl, MZpart);
  hipLaunchKernelGGL(dotatt_out, dim3(1024), dim3(256), 0, stream,
                     V, Qh, Ql, Kh, Kl, MZpart, Out);
}